// Round 1
// baseline (5389.723 us; speedup 1.0000x reference)
//
#include <hip/hip_runtime.h>
#include <hip/hip_bf16.h>

#define B_N 4
#define C_N 512
#define F_N 4
#define HW_N 784
#define PL (F_N * HW_N)      // 3136 elements per (b,c) plane
#define SCALE_F 0.125f

// ---------------- conv 1x3x3 (spatial, per (b,f) plane) ----------------
// out[b,co,f,s] = sum_{ci,ky,kx} in[b,ci,f,y+ky-1,x+kx-1] * wt[co,ci,ky,kx]
__global__ __launch_bounds__(256) void conv133_kernel(
    const float* __restrict__ in, const float* __restrict__ wt,
    float* __restrict__ out)
{
  const int bf  = blockIdx.x;        // 16  (b*4+f)
  const int cot = blockIdx.y;        // 8   (64-channel tile)
  const int rt  = blockIdx.z;        // 7   (4-row tile)
  const int b = bf >> 2, f = bf & 3;
  const int cobase = cot << 6;
  const int y0 = rt << 2;
  const int t = threadIdx.x;
  const int a  = t & 15;             // spatial lane
  const int tb = t >> 4;             // channel lane

  __shared__ float xs[8 * 6 * 32];   // [ci][ry(6)][cx(32, cols 0..29 used)]
  __shared__ float wfs[64 * 72];     // [co][ci*9+tap]

  float acc[4][7];
  #pragma unroll
  for (int i = 0; i < 4; ++i)
    #pragma unroll
    for (int j = 0; j < 7; ++j) acc[i][j] = 0.f;

  int xoff[7];
  #pragma unroll
  for (int j = 0; j < 7; ++j) {
    int s = a + 16 * j;              // 0..111 within tile (4 rows x 28)
    xoff[j] = (s / 28) * 32 + (s % 28);
  }

  const float* inb = in + ((size_t)b * C_N) * PL + (size_t)f * HW_N;

  for (int cib = 0; cib < C_N; cib += 8) {
    __syncthreads();
    // stage x tile with halo, zero-padded
    for (int l = t; l < 8 * 6 * 30; l += 256) {
      int ci = l / 180;
      int rem = l - ci * 180;
      int ry = rem / 30;
      int cx = rem - ry * 30;
      int y = y0 - 1 + ry;
      int x = cx - 1;
      float v = 0.f;
      if ((unsigned)y < 28u && (unsigned)x < 28u)
        v = inb[(size_t)(cib + ci) * PL + y * 28 + x];
      xs[(ci * 6 + ry) * 32 + cx] = v;
    }
    // stage weights [64co][8ci][9tap]
    for (int l = t; l < 64 * 72; l += 256) {
      int co = l / 72;
      int rem = l - co * 72;
      wfs[l] = wt[((size_t)(cobase + co) * C_N + cib) * 9 + rem];
    }
    __syncthreads();
    for (int ci = 0; ci < 8; ++ci) {
      const float* xsc = xs + ci * 192;
      const float* wfc = wfs + ci * 9;
      #pragma unroll
      for (int dky = 0; dky < 3; ++dky) {
        #pragma unroll
        for (int dkx = 0; dkx < 3; ++dkx) {
          const int tap = dky * 3 + dkx;
          float wr[4];
          #pragma unroll
          for (int i = 0; i < 4; ++i) wr[i] = wfc[(tb + 16 * i) * 72 + tap];
          #pragma unroll
          for (int j = 0; j < 7; ++j) {
            float xv = xsc[xoff[j] + dky * 32 + dkx];
            #pragma unroll
            for (int i = 0; i < 4; ++i) acc[i][j] = fmaf(wr[i], xv, acc[i][j]);
          }
        }
      }
    }
  }
  const int s0 = rt * 112;
  #pragma unroll
  for (int i = 0; i < 4; ++i) {
    float* o = out + ((size_t)(b * C_N + cobase + tb + 16 * i)) * PL
                   + (size_t)f * HW_N + s0;
    #pragma unroll
    for (int j = 0; j < 7; ++j) o[a + 16 * j] = acc[i][j];
  }
}

// ---------------- conv 3x1x1 (temporal) ----------------
// out[b,co,f,s] = sum_{ci,kf} in[b,ci,f+kf-1,s] * wt[co,ci,kf]
__global__ __launch_bounds__(256) void conv311_kernel(
    const float* __restrict__ in, const float* __restrict__ wt,
    float* __restrict__ out)
{
  const int bf  = blockIdx.x;        // 16
  const int cot = blockIdx.y;        // 8
  const int st  = blockIdx.z;        // 7 (112-wide s tile)
  const int b = bf >> 2, f = bf & 3;
  const int cobase = cot << 6;
  const int s0 = st * 112;
  const int t = threadIdx.x;
  const int a  = t & 15;
  const int tb = t >> 4;

  __shared__ float xs[8 * 3 * 112];  // [ci][kf][ss]
  __shared__ float wfs[64 * 24];     // [co][ci*3+kf]

  float acc[4][7];
  #pragma unroll
  for (int i = 0; i < 4; ++i)
    #pragma unroll
    for (int j = 0; j < 7; ++j) acc[i][j] = 0.f;

  const float* inb = in + ((size_t)b * C_N) * PL;

  for (int cib = 0; cib < C_N; cib += 8) {
    __syncthreads();
    for (int l = t; l < 8 * 3 * 112; l += 256) {
      int ci = l / 336;
      int rem = l - ci * 336;
      int kf = rem / 112;
      int ss = rem - kf * 112;
      int fr = f - 1 + kf;
      float v = 0.f;
      if ((unsigned)fr < 4u)
        v = inb[(size_t)(cib + ci) * PL + fr * HW_N + s0 + ss];
      xs[l] = v;
    }
    for (int l = t; l < 64 * 24; l += 256) {
      int co = l / 24;
      int rem = l - co * 24;
      wfs[l] = wt[((size_t)(cobase + co) * C_N + cib) * 3 + rem];
    }
    __syncthreads();
    for (int ci = 0; ci < 8; ++ci) {
      #pragma unroll
      for (int kf = 0; kf < 3; ++kf) {
        float wr[4];
        #pragma unroll
        for (int i = 0; i < 4; ++i) wr[i] = wfs[(tb + 16 * i) * 24 + ci * 3 + kf];
        const float* xrow = xs + ci * 336 + kf * 112;
        #pragma unroll
        for (int j = 0; j < 7; ++j) {
          float xv = xrow[a + 16 * j];
          #pragma unroll
          for (int i = 0; i < 4; ++i) acc[i][j] = fmaf(wr[i], xv, acc[i][j]);
        }
      }
    }
  }
  #pragma unroll
  for (int i = 0; i < 4; ++i) {
    float* o = out + ((size_t)(b * C_N + cobase + tb + 16 * i)) * PL
                   + (size_t)f * HW_N + s0;
    #pragma unroll
    for (int j = 0; j < 7; ++j) o[a + 16 * j] = acc[i][j];
  }
}

// ---------------- fused attention per (b, 16-channel slab) ----------------
// For group g=(b, cbase): contiguous slab [64][784]. S = scale*(Q^T K + P Q),
// A = softmax_rows(S), O = V A^T, out = O + rel2.
__global__ __launch_bounds__(256) void attn_kernel(
    const float* __restrict__ q0, const float* __restrict__ k0,
    const float* __restrict__ v0,
    const float* __restrict__ rel_h, const float* __restrict__ rel_w,
    const float* __restrict__ rel_t, const float* __restrict__ rel_h2,
    const float* __restrict__ rel_w2, const float* __restrict__ rel_t2,
    float* __restrict__ out)
{
  const int g  = blockIdx.x;         // 128 groups
  const int qc = blockIdx.y;         // 14 q-chunks of 56
  const int b = g >> 5, gg = g & 31;
  const int cbase = gg << 4;
  const int h = gg >> 2, f = gg & 3;
  const int qbase = qc * 56;
  const int t = threadIdx.x;
  const int wv = t >> 6, lane = t & 63;
  const int qr0 = wv * 14;           // this wave's 14 q-rows (local)

  const size_t slab = ((size_t)b * 2048 + (size_t)cbase * 4) * 784;
  const float* Q = q0 + slab;
  const float* K = k0 + slab;
  const float* V = v0 + slab;

  __shared__ __align__(16) float Qc[64 * 57];    // Q[d][q-chunk], stride 57
  __shared__ __align__(16) float Pp[56 * 65];    // P[q][d], stride 65
  __shared__ __align__(16) float ktvt[64 * 65];  // Kt[64][64] -> Vt[k][d] s65 -> Osh
  __shared__ __align__(16) float qtas[64 * 64];  // Qt[64][64] -> As[q][k] s65

  for (int l = t; l < 64 * 56; l += 256) {
    int d = l / 56;
    int q = l - d * 56;
    Qc[d * 57 + q] = Q[(size_t)d * 784 + qbase + q];
  }
  for (int l = t; l < 56 * 64; l += 256) {
    int q = l >> 6;
    int d = l & 63;
    int s = qbase + q;
    int idx = (h << 6) + d;
    Pp[q * 65 + d] = rel_h[idx * 28 + s / 28] + rel_w[idx * 28 + s % 28]
                   + rel_t[idx * 4 + f];
  }

  float S[14], O[14], mm[14], ll[14];
  #pragma unroll
  for (int i = 0; i < 14; ++i) { O[i] = 0.f; mm[i] = -1e30f; ll[i] = 0.f; }

  for (int kt = 0; kt < 13; ++kt) {
    const int kbase = kt * 64;
    __syncthreads();   // prev PV (Vt/As) done before restage
    {
      const int d = t >> 2, c0 = (t & 3) << 4;
      if (kbase + 64 <= 784) {
        const float4* Kr = (const float4*)(K + (size_t)d * 784 + kbase + c0);
        const float4* Qr = (const float4*)(Q + (size_t)d * 784 + kbase + c0);
        #pragma unroll
        for (int r = 0; r < 4; ++r) {
          *(float4*)&ktvt[d * 64 + c0 + 4 * r] = Kr[r];
          *(float4*)&qtas[d * 64 + c0 + 4 * r] = Qr[r];
        }
      } else {
        for (int r = 0; r < 16; ++r) {
          int col = c0 + r;
          int kk = kbase + col;
          float kv = 0.f, qv = 0.f;
          if (kk < 784) { kv = K[(size_t)d * 784 + kk]; qv = Q[(size_t)d * 784 + kk]; }
          ktvt[d * 64 + col] = kv;
          qtas[d * 64 + col] = qv;
        }
      }
    }
    __syncthreads();
    #pragma unroll
    for (int i = 0; i < 14; ++i) S[i] = 0.f;
    #pragma unroll 4
    for (int d = 0; d < 64; ++d) {
      float kv = ktvt[d * 64 + lane];
      float qt = qtas[d * 64 + lane];
      const float* qcrow = Qc + d * 57 + qr0;
      const float* prow  = Pp + qr0 * 65 + d;
      #pragma unroll
      for (int i = 0; i < 14; ++i)
        S[i] = fmaf(qcrow[i], kv, fmaf(prow[i * 65], qt, S[i]));
    }
    __syncthreads();   // Kt/Qt reads done; now reuse buffers
    {
      const int d = t >> 2, c0 = (t & 3) << 4;
      if (kbase + 64 <= 784) {
        const float4* Vr = (const float4*)(V + (size_t)d * 784 + kbase + c0);
        #pragma unroll
        for (int r = 0; r < 4; ++r) {
          float4 vv = Vr[r];
          int col = c0 + 4 * r;
          ktvt[(col + 0) * 65 + d] = vv.x;
          ktvt[(col + 1) * 65 + d] = vv.y;
          ktvt[(col + 2) * 65 + d] = vv.z;
          ktvt[(col + 3) * 65 + d] = vv.w;
        }
      } else {
        for (int r = 0; r < 16; ++r) {
          int col = c0 + r;
          int kk = kbase + col;
          ktvt[col * 65 + d] = (kk < 784) ? V[(size_t)d * 784 + kk] : 0.f;
        }
      }
    }
    const bool kvalid = (kbase + lane) < 784;
    #pragma unroll
    for (int i = 0; i < 14; ++i) {
      float s_ = kvalid ? S[i] * SCALE_F : -1e30f;
      float tm = s_;
      #pragma unroll
      for (int off = 32; off >= 1; off >>= 1)
        tm = fmaxf(tm, __shfl_xor(tm, off));
      float mn = fmaxf(mm[i], tm);
      float sc = __expf(mm[i] - mn);
      float p  = __expf(s_ - mn);
      float ps = p;
      #pragma unroll
      for (int off = 32; off >= 1; off >>= 1)
        ps += __shfl_xor(ps, off);
      ll[i] = ll[i] * sc + ps;
      O[i] *= sc;
      mm[i] = mn;
      qtas[(qr0 + i) * 65 + lane] = p;   // As[q][k]
    }
    __syncthreads();
    #pragma unroll 2
    for (int k = 0; k < 64; ++k) {
      float v = ktvt[k * 65 + lane];     // Vt[k][d=lane]
      const float* arow = qtas + qr0 * 65 + k;
      #pragma unroll
      for (int i = 0; i < 14; ++i)
        O[i] = fmaf(arow[i * 65], v, O[i]);
    }
  }
  __syncthreads();
  #pragma unroll
  for (int i = 0; i < 14; ++i)
    ktvt[(qr0 + i) * 65 + lane] = O[i] / ll[i];   // Osh[q][d]
  __syncthreads();
  {
    const int dch = t >> 2;            // di 0..63
    const int part = t & 3;
    const int c  = cbase + (dch >> 2); // mixed-reshape channel
    const int ff = dch & 3;            // mixed-reshape frame
    const float rtv = rel_t2[c * 4 + ff];
    const float* rh2 = rel_h2 + c * 28;
    const float* rw2 = rel_w2 + c * 28;
    float* orow = out + ((size_t)(b * C_N + c)) * PL + (size_t)ff * HW_N + qbase;
    #pragma unroll
    for (int j = 0; j < 14; ++j) {
      int sl = part * 14 + j;
      int s = qbase + sl;
      orow[sl] = ktvt[sl * 65 + dch] + rtv + rh2[s / 28] + rw2[s % 28];
    }
  }
}

extern "C" void kernel_launch(void* const* d_in, const int* in_sizes, int n_in,
                              void* d_out, int out_size, void* d_ws, size_t ws_size,
                              hipStream_t stream) {
  const float* x     = (const float*)d_in[0];
  const float* Wq    = (const float*)d_in[1];
  const float* Wk    = (const float*)d_in[2];
  const float* Wv1   = (const float*)d_in[3];
  const float* Wv2   = (const float*)d_in[4];
  const float* relh  = (const float*)d_in[5];
  const float* relw  = (const float*)d_in[6];
  const float* relt  = (const float*)d_in[7];
  const float* relh2 = (const float*)d_in[8];
  const float* relw2 = (const float*)d_in[9];
  const float* relt2 = (const float*)d_in[10];
  float* out = (float*)d_out;
  float* ws  = (float*)d_ws;

  const size_t NB = (size_t)B_N * C_N * PL;   // 6,422,528 elements
  float* t0 = ws;            // tmp (v stage 1), later q0
  float* k0 = ws + NB;
  float* v0 = ws + 2 * NB;

  dim3 blk(256);
  dim3 cgrid(16, 8, 7);
  // v = conv133(conv311(x, Wv1), Wv2)
  hipLaunchKernelGGL(conv311_kernel, cgrid, blk, 0, stream, x, Wv1, t0);
  hipLaunchKernelGGL(conv133_kernel, cgrid, blk, 0, stream, t0, Wv2, v0);
  // k = conv311(x, Wk)
  hipLaunchKernelGGL(conv311_kernel, cgrid, blk, 0, stream, x, Wk, k0);
  // q = conv133(x, Wq) (reuses tmp slot, safe via stream ordering)
  hipLaunchKernelGGL(conv133_kernel, cgrid, blk, 0, stream, x, Wq, t0);
  // fused attention + rel2 epilogue
  hipLaunchKernelGGL(attn_kernel, dim3(128, 14), blk, 0, stream,
                     t0, k0, v0, relh, relw, relt, relh2, relw2, relt2, out);
}

// Round 2
// 1581.637 us; speedup vs baseline: 3.4077x; 3.4077x over previous
//
#include <hip/hip_runtime.h>
#include <hip/hip_bf16.h>

#define B_N 4
#define C_N 512
#define F_N 4
#define HW_N 784
#define PL (F_N * HW_N)        // 3136 per (b,c) plane
#define NTOT 12544             // 16 * 784 columns
#define SCALE_F 0.125f

typedef unsigned short u16;
typedef __attribute__((ext_vector_type(8))) short bf16x8;
typedef __attribute__((ext_vector_type(4))) float f32x4;
typedef __attribute__((ext_vector_type(8))) unsigned short ushort8;

__device__ __forceinline__ u16 f2b(float x) {
  unsigned u = __float_as_uint(x);
  unsigned r = ((u >> 16) & 1u) + 0x7fffu;
  return (u16)((u + r) >> 16);
}
__device__ __forceinline__ float b2f(u16 u) {
  return __uint_as_float(((unsigned)u) << 16);
}

typedef const __attribute__((address_space(1))) unsigned int* gas_ptr;
typedef __attribute__((address_space(3))) unsigned int* las_ptr;
__device__ __forceinline__ void gl_lds16(const void* g, void* l) {
  __builtin_amdgcn_global_load_lds((gas_ptr)(unsigned long long)(g),
                                   (las_ptr)(unsigned)(unsigned long long)(l),
                                   16, 0, 0);
}

// ---------------- zero small pad buffer ----------------
__global__ void zerok(float* z) { z[blockIdx.x * 256 + threadIdx.x] = 0.f; }

// ---------------- weight pack: [co][ci][TAPS] f32 -> [tap][co][ci] bf16 ----
template<int TAPS>
__global__ __launch_bounds__(256) void pack_w(const float* __restrict__ w,
                                              u16* __restrict__ wb, int ntot) {
  int o = blockIdx.x * 256 + threadIdx.x;
  if (o >= ntot) return;
  int tap = o / (C_N * C_N);
  int rem = o - tap * (C_N * C_N);          // co*512 + ci
  wb[o] = f2b(w[(size_t)rem * TAPS + tap]);
}

// ---------------- cast+transpose: x f32 NCDHW -> xt bf16 [bf*784+s][512] ----
__global__ __launch_bounds__(256) void cast_transpose(const float* __restrict__ x,
                                                      u16* __restrict__ xt) {
  const int bf = blockIdx.x, st = blockIdx.y, ct = blockIdx.z;
  const int b = bf >> 2, f = bf & 3;
  const int s0 = st * 64, c0 = ct * 64;
  const int tx = threadIdx.x & 63, ty = threadIdx.x >> 6;
  __shared__ float tile[64][65];
  const float* src = x + ((size_t)(b * C_N + c0)) * PL + (size_t)f * HW_N + s0;
  #pragma unroll
  for (int i = 0; i < 16; ++i) {
    int c = ty + i * 4;
    float v = 0.f;
    if (s0 + tx < HW_N) v = src[(size_t)c * PL + tx];
    tile[c][tx] = v;
  }
  __syncthreads();
  #pragma unroll
  for (int i = 0; i < 16; ++i) {
    int srow = ty + i * 4;
    int ss = s0 + srow;
    if (ss < HW_N) xt[((size_t)bf * HW_N + ss) * C_N + c0 + tx] = f2b(tile[tx][srow]);
  }
}

// ---------------- MFMA implicit-GEMM conv ----------------
// xin: bf16 channels-last [12544][512]; wb: bf16 [TAPS][512][512]
// OUTM=1: bf16 channels-last [12544][512] ; OUTM=2: bf16 planar [b][co][f][s]
template<int TAPS, int OUTM>
__global__ __launch_bounds__(256) void conv_mfma(
    const u16* __restrict__ xin, const u16* __restrict__ wb,
    u16* __restrict__ outp, const u16* __restrict__ zbuf)
{
  const int nt = blockIdx.x;       // 98
  const int cot = blockIdx.y;      // 4
  const int cobase = cot << 7;
  const int t = threadIdx.x;
  const int wv = t >> 6, l = t & 63;
  const int wm = wv >> 1, wn = wv & 1;

  __shared__ u16 Xs[128 * 64];     // [col][ci] swizzled, 16KB
  __shared__ u16 Ws[128 * 64];     // [co][ci] swizzled, 16KB

  const int crow = l >> 3;                     // 0..7
  const int chunk = (l & 7) ^ (crow & 7);      // pre-swizzled source chunk

  int gcol[4], sy[4], sx[4], sf[4];
  #pragma unroll
  for (int i = 0; i < 4; ++i) {
    gcol[i] = nt * 128 + wv * 32 + i * 8 + crow;
    int s = gcol[i] % HW_N;
    sy[i] = s / 28; sx[i] = s - (s / 28) * 28;
    sf[i] = (gcol[i] / HW_N) & 3;
  }

  f32x4 acc[4][4];
  #pragma unroll
  for (int fm = 0; fm < 4; ++fm)
    #pragma unroll
    for (int fn = 0; fn < 4; ++fn) acc[fm][fn] = (f32x4){0.f, 0.f, 0.f, 0.f};

  for (int tap = 0; tap < TAPS; ++tap) {
    const u16* xp[4];
    const u16* wp[4];
    int dy = 0, dx = 0, off;
    if (TAPS == 9) { dy = tap / 3; dx = tap - dy * 3; off = (dy - 1) * 28 + (dx - 1); }
    else           { off = (tap - 1) * HW_N; }
    #pragma unroll
    for (int i = 0; i < 4; ++i) {
      bool valid;
      if (TAPS == 9) {
        int yy = sy[i] + dy - 1, xx = sx[i] + dx - 1;
        valid = ((unsigned)yy < 28u) && ((unsigned)xx < 28u);
      } else {
        int ff = sf[i] + tap - 1;
        valid = ((unsigned)ff < 4u);
      }
      xp[i] = valid ? (xin + (size_t)(gcol[i] + off) * C_N + chunk * 8)
                    : (zbuf + chunk * 8);
      int co = cobase + wv * 32 + i * 8 + crow;
      wp[i] = wb + ((size_t)tap * C_N + co) * C_N + chunk * 8;
    }
    for (int kb = 0; kb < 8; ++kb) {
      __syncthreads();                       // prior MFMA LDS reads done
      #pragma unroll
      for (int i = 0; i < 4; ++i) {
        gl_lds16(xp[i], (void*)(Xs + (wv * 4 + i) * 512));
        gl_lds16(wp[i], (void*)(Ws + (wv * 4 + i) * 512));
        xp[i] += 64; wp[i] += 64;
      }
      __syncthreads();                       // drains vmcnt -> tiles ready
      const int lr = l & 15, lk = l >> 4;
      #pragma unroll
      for (int kk = 0; kk < 2; ++kk) {
        const int slotbase = kk * 4 + lk;
        bf16x8 af[4], bx[4];
        #pragma unroll
        for (int fm = 0; fm < 4; ++fm) {
          int row = wm * 64 + fm * 16 + lr;
          int slot = slotbase ^ (lr & 7);
          af[fm] = *(const bf16x8*)&Ws[row * 64 + slot * 8];
        }
        #pragma unroll
        for (int fn = 0; fn < 4; ++fn) {
          int col = wn * 64 + fn * 16 + lr;
          int slot = slotbase ^ (lr & 7);
          bx[fn] = *(const bf16x8*)&Xs[col * 64 + slot * 8];
        }
        #pragma unroll
        for (int fm = 0; fm < 4; ++fm)
          #pragma unroll
          for (int fn = 0; fn < 4; ++fn)
            acc[fm][fn] = __builtin_amdgcn_mfma_f32_16x16x32_bf16(
                af[fm], bx[fn], acc[fm][fn], 0, 0, 0);
      }
    }
  }

  // epilogue: C row = co (A-rows), col = n (B-rows); col=lane&15, row=(lane>>4)*4+r
  const int lr = l & 15, lg = l >> 4;
  #pragma unroll
  for (int fn = 0; fn < 4; ++fn) {
    int n = nt * 128 + wn * 64 + fn * 16 + lr;
    if (OUTM == 1) {
      #pragma unroll
      for (int fm = 0; fm < 4; ++fm) {
        int co = cobase + wm * 64 + fm * 16 + lg * 4;
        ushort4 pk;
        pk.x = f2b(acc[fm][fn][0]); pk.y = f2b(acc[fm][fn][1]);
        pk.z = f2b(acc[fm][fn][2]); pk.w = f2b(acc[fm][fn][3]);
        *(ushort4*)&outp[(size_t)n * C_N + co] = pk;
      }
    } else {
      int bf = n / HW_N, s = n - (n / HW_N) * HW_N;
      int b = bf >> 2, f = bf & 3;
      #pragma unroll
      for (int fm = 0; fm < 4; ++fm) {
        int co = cobase + wm * 64 + fm * 16 + lg * 4;
        size_t base = ((size_t)(b * C_N + co)) * PL + (size_t)f * HW_N + s;
        outp[base]            = f2b(acc[fm][fn][0]);
        outp[base + PL]       = f2b(acc[fm][fn][1]);
        outp[base + 2 * PL]   = f2b(acc[fm][fn][2]);
        outp[base + 3 * PL]   = f2b(acc[fm][fn][3]);
      }
    }
  }
}

// ---------------- fused attention (f32 math, bf16 Q/K/V planar) ----------------
__global__ __launch_bounds__(256) void attn_kernel(
    const u16* __restrict__ q0, const u16* __restrict__ k0,
    const u16* __restrict__ v0,
    const float* __restrict__ rel_h, const float* __restrict__ rel_w,
    const float* __restrict__ rel_t, const float* __restrict__ rel_h2,
    const float* __restrict__ rel_w2, const float* __restrict__ rel_t2,
    float* __restrict__ out)
{
  const int g  = blockIdx.x;         // 128 groups
  const int qc = blockIdx.y;         // 14 q-chunks of 56
  const int b = g >> 5, gg = g & 31;
  const int cbase = gg << 4;
  const int h = gg >> 2, f = gg & 3;
  const int qbase = qc * 56;
  const int t = threadIdx.x;
  const int wv = t >> 6, lane = t & 63;
  const int qr0 = wv * 14;

  const size_t slab = ((size_t)b * 2048 + (size_t)cbase * 4) * 784;
  const u16* Q = q0 + slab;
  const u16* K = k0 + slab;
  const u16* V = v0 + slab;

  __shared__ __align__(16) float Qc[64 * 57];
  __shared__ __align__(16) float Pp[56 * 65];
  __shared__ __align__(16) float ktvt[64 * 65];
  __shared__ __align__(16) float qtas[64 * 64];

  for (int l = t; l < 64 * 56; l += 256) {
    int d = l / 56;
    int q = l - d * 56;
    Qc[d * 57 + q] = b2f(Q[(size_t)d * 784 + qbase + q]);
  }
  for (int l = t; l < 56 * 64; l += 256) {
    int q = l >> 6;
    int d = l & 63;
    int s = qbase + q;
    int idx = (h << 6) + d;
    Pp[q * 65 + d] = rel_h[idx * 28 + s / 28] + rel_w[idx * 28 + s % 28]
                   + rel_t[idx * 4 + f];
  }

  float S[14], O[14], mm[14], ll[14];
  #pragma unroll
  for (int i = 0; i < 14; ++i) { O[i] = 0.f; mm[i] = -1e30f; ll[i] = 0.f; }

  for (int kt = 0; kt < 13; ++kt) {
    const int kbase = kt * 64;
    __syncthreads();
    {
      const int d = t >> 2, c0 = (t & 3) << 4;
      if (kbase + 64 <= 784) {
        const u16* Krp = K + (size_t)d * 784 + kbase + c0;
        const u16* Qrp = Q + (size_t)d * 784 + kbase + c0;
        ushort8 kv0 = *(const ushort8*)Krp, kv1 = *(const ushort8*)(Krp + 8);
        ushort8 qv0 = *(const ushort8*)Qrp, qv1 = *(const ushort8*)(Qrp + 8);
        #pragma unroll
        for (int j = 0; j < 8; ++j) {
          ktvt[d * 64 + c0 + j]     = b2f(kv0[j]);
          ktvt[d * 64 + c0 + 8 + j] = b2f(kv1[j]);
          qtas[d * 64 + c0 + j]     = b2f(qv0[j]);
          qtas[d * 64 + c0 + 8 + j] = b2f(qv1[j]);
        }
      } else {
        for (int r = 0; r < 16; ++r) {
          int col = c0 + r;
          int kk = kbase + col;
          float kv = 0.f, qv = 0.f;
          if (kk < 784) { kv = b2f(K[(size_t)d * 784 + kk]); qv = b2f(Q[(size_t)d * 784 + kk]); }
          ktvt[d * 64 + col] = kv;
          qtas[d * 64 + col] = qv;
        }
      }
    }
    __syncthreads();
    #pragma unroll
    for (int i = 0; i < 14; ++i) S[i] = 0.f;
    #pragma unroll 4
    for (int d = 0; d < 64; ++d) {
      float kv = ktvt[d * 64 + lane];
      float qt = qtas[d * 64 + lane];
      const float* qcrow = Qc + d * 57 + qr0;
      const float* prow  = Pp + qr0 * 65 + d;
      #pragma unroll
      for (int i = 0; i < 14; ++i)
        S[i] = fmaf(qcrow[i], kv, fmaf(prow[i * 65], qt, S[i]));
    }
    __syncthreads();
    {
      const int d = t >> 2, c0 = (t & 3) << 4;
      if (kbase + 64 <= 784) {
        const u16* Vrp = V + (size_t)d * 784 + kbase + c0;
        ushort8 vv0 = *(const ushort8*)Vrp, vv1 = *(const ushort8*)(Vrp + 8);
        #pragma unroll
        for (int j = 0; j < 8; ++j) {
          ktvt[(c0 + j) * 65 + d]     = b2f(vv0[j]);
          ktvt[(c0 + 8 + j) * 65 + d] = b2f(vv1[j]);
        }
      } else {
        for (int r = 0; r < 16; ++r) {
          int col = c0 + r;
          int kk = kbase + col;
          ktvt[col * 65 + d] = (kk < 784) ? b2f(V[(size_t)d * 784 + kk]) : 0.f;
        }
      }
    }
    const bool kvalid = (kbase + lane) < 784;
    #pragma unroll
    for (int i = 0; i < 14; ++i) {
      float s_ = kvalid ? S[i] * SCALE_F : -1e30f;
      float tm = s_;
      #pragma unroll
      for (int off = 32; off >= 1; off >>= 1)
        tm = fmaxf(tm, __shfl_xor(tm, off));
      float mn = fmaxf(mm[i], tm);
      float sc = __expf(mm[i] - mn);
      float p  = __expf(s_ - mn);
      float ps = p;
      #pragma unroll
      for (int off = 32; off >= 1; off >>= 1)
        ps += __shfl_xor(ps, off);
      ll[i] = ll[i] * sc + ps;
      O[i] *= sc;
      mm[i] = mn;
      qtas[(qr0 + i) * 65 + lane] = p;
    }
    __syncthreads();
    #pragma unroll 2
    for (int k = 0; k < 64; ++k) {
      float v = ktvt[k * 65 + lane];
      const float* arow = qtas + qr0 * 65 + k;
      #pragma unroll
      for (int i = 0; i < 14; ++i)
        O[i] = fmaf(arow[i * 65], v, O[i]);
    }
  }
  __syncthreads();
  #pragma unroll
  for (int i = 0; i < 14; ++i)
    ktvt[(qr0 + i) * 65 + lane] = O[i] / ll[i];
  __syncthreads();
  {
    const int dch = t >> 2;
    const int part = t & 3;
    const int c  = cbase + (dch >> 2);
    const int ff = dch & 3;
    const float rtv = rel_t2[c * 4 + ff];
    const float* rh2 = rel_h2 + c * 28;
    const float* rw2 = rel_w2 + c * 28;
    float* orow = out + ((size_t)(b * C_N + c)) * PL + (size_t)ff * HW_N + qbase;
    #pragma unroll
    for (int j = 0; j < 14; ++j) {
      int sl = part * 14 + j;
      int s = qbase + sl;
      orow[sl] = ktvt[sl * 65 + dch] + rtv + rh2[s / 28] + rw2[s % 28];
    }
  }
}

extern "C" void kernel_launch(void* const* d_in, const int* in_sizes, int n_in,
                              void* d_out, int out_size, void* d_ws, size_t ws_size,
                              hipStream_t stream) {
  const float* x     = (const float*)d_in[0];
  const float* Wq    = (const float*)d_in[1];
  const float* Wk    = (const float*)d_in[2];
  const float* Wv1   = (const float*)d_in[3];
  const float* Wv2   = (const float*)d_in[4];
  const float* relh  = (const float*)d_in[5];
  const float* relw  = (const float*)d_in[6];
  const float* relt  = (const float*)d_in[7];
  const float* relh2 = (const float*)d_in[8];
  const float* relw2 = (const float*)d_in[9];
  const float* relt2 = (const float*)d_in[10];
  float* out = (float*)d_out;
  char* ws = (char*)d_ws;

  const size_t NE = (size_t)NTOT * C_N;          // 6,422,528 elements
  u16* xt   = (u16*)(ws);                        // NE bf16
  u16* tq   = (u16*)(ws + NE * 2);               // t_bt then q0 (both NE bf16)
  u16* k0   = (u16*)(ws + NE * 4);
  u16* v0   = (u16*)(ws + NE * 6);
  u16* wqb  = (u16*)(ws + NE * 8);                               // 9*512*512
  u16* wkb  = (u16*)(ws + NE * 8 + 4718592);                     // 3*512*512
  u16* wv1b = (u16*)(ws + NE * 8 + 4718592 + 1572864);
  u16* wv2b = (u16*)(ws + NE * 8 + 4718592 + 2 * 1572864);
  u16* zbuf = (u16*)(ws + NE * 8 + 2 * 4718592 + 2 * 1572864);   // 4KB zeros

  zerok<<<dim3(4), dim3(256), 0, stream>>>((float*)zbuf);
  pack_w<9><<<dim3(9216), dim3(256), 0, stream>>>(Wq,  wqb,  9 * C_N * C_N);
  pack_w<3><<<dim3(3072), dim3(256), 0, stream>>>(Wk,  wkb,  3 * C_N * C_N);
  pack_w<3><<<dim3(3072), dim3(256), 0, stream>>>(Wv1, wv1b, 3 * C_N * C_N);
  pack_w<9><<<dim3(9216), dim3(256), 0, stream>>>(Wv2, wv2b, 9 * C_N * C_N);
  cast_transpose<<<dim3(16, 13, 8), dim3(256), 0, stream>>>(x, xt);

  dim3 cgrid(98, 4), blk(256);
  // v1 = conv311(x, Wv1) -> bf16 channels-last
  conv_mfma<3, 1><<<cgrid, blk, 0, stream>>>(xt, wv1b, tq, zbuf);
  // v = conv133(v1, Wv2) -> bf16 planar
  conv_mfma<9, 2><<<cgrid, blk, 0, stream>>>(tq, wv2b, v0, zbuf);
  // k = conv311(x, Wk) -> bf16 planar
  conv_mfma<3, 2><<<cgrid, blk, 0, stream>>>(xt, wkb, k0, zbuf);
  // q = conv133(x, Wq) -> bf16 planar (overwrites dead t_bt region)
  conv_mfma<9, 2><<<cgrid, blk, 0, stream>>>(xt, wqb, tq, zbuf);

  attn_kernel<<<dim3(128, 14), blk, 0, stream>>>(
      tq, k0, v0, relh, relw, relt, relh2, relw2, relt2, out);
}

// Round 3
// 467.262 us; speedup vs baseline: 11.5347x; 3.3849x over previous
//
#include <hip/hip_runtime.h>
#include <hip/hip_bf16.h>

#define B_N 4
#define C_N 512
#define F_N 4
#define HW_N 784
#define PL (F_N * HW_N)        // 3136 per (b,c) plane
#define NTOT 12544             // 16 * 784 columns
#define SCALE_F 0.125f

typedef unsigned short u16;
typedef __attribute__((ext_vector_type(8))) short bf16x8;
typedef __attribute__((ext_vector_type(4))) float f32x4;
typedef __attribute__((ext_vector_type(8))) unsigned short ushort8;

__device__ __forceinline__ u16 f2b(float x) {
  unsigned u = __float_as_uint(x);
  unsigned r = ((u >> 16) & 1u) + 0x7fffu;
  return (u16)((u + r) >> 16);
}
__device__ __forceinline__ float b2f(u16 u) {
  return __uint_as_float(((unsigned)u) << 16);
}

typedef const __attribute__((address_space(1))) unsigned int* gas_ptr;
typedef __attribute__((address_space(3))) unsigned int* las_ptr;
__device__ __forceinline__ void gl_lds16(const void* g, void* l) {
  __builtin_amdgcn_global_load_lds((gas_ptr)(unsigned long long)(g),
                                   (las_ptr)(unsigned)(unsigned long long)(l),
                                   16, 0, 0);
}

// ---------------- zero small pad buffer ----------------
__global__ void zerok(float* z) { z[blockIdx.x * 256 + threadIdx.x] = 0.f; }

// ---------------- weight pack: [co][ci][TAPS] f32 -> [tap][co][ci] bf16 ----
template<int TAPS>
__global__ __launch_bounds__(256) void pack_w(const float* __restrict__ w,
                                              u16* __restrict__ wb, int ntot) {
  int o = blockIdx.x * 256 + threadIdx.x;
  if (o >= ntot) return;
  int tap = o / (C_N * C_N);
  int rem = o - tap * (C_N * C_N);          // co*512 + ci
  wb[o] = f2b(w[(size_t)rem * TAPS + tap]);
}

// ---------------- cast+transpose: x f32 NCDHW -> xt bf16 [bf*784+s][512] ----
__global__ __launch_bounds__(256) void cast_transpose(const float* __restrict__ x,
                                                      u16* __restrict__ xt) {
  const int bf = blockIdx.x, st = blockIdx.y, ct = blockIdx.z;
  const int b = bf >> 2, f = bf & 3;
  const int s0 = st * 64, c0 = ct * 64;
  const int tx = threadIdx.x & 63, ty = threadIdx.x >> 6;
  __shared__ float tile[64][65];
  const float* src = x + ((size_t)(b * C_N + c0)) * PL + (size_t)f * HW_N + s0;
  #pragma unroll
  for (int i = 0; i < 16; ++i) {
    int c = ty + i * 4;
    float v = 0.f;
    if (s0 + tx < HW_N) v = src[(size_t)c * PL + tx];
    tile[c][tx] = v;
  }
  __syncthreads();
  #pragma unroll
  for (int i = 0; i < 16; ++i) {
    int srow = ty + i * 4;
    int ss = s0 + srow;
    if (ss < HW_N) xt[((size_t)bf * HW_N + ss) * C_N + c0 + tx] = f2b(tile[tx][srow]);
  }
}

// ---------------- MFMA implicit-GEMM conv ----------------
// xin: bf16 channels-last [12544][512]; wb: bf16 [TAPS][512][512]
// OUTM=1: bf16 channels-last [12544][512] ; OUTM=2: bf16 planar [b][co][f][s]
template<int TAPS, int OUTM>
__global__ __launch_bounds__(256) void conv_mfma(
    const u16* __restrict__ xin, const u16* __restrict__ wb,
    u16* __restrict__ outp, const u16* __restrict__ zbuf)
{
  const int nt = blockIdx.x;       // 98
  const int cot = blockIdx.y;      // 4
  const int cobase = cot << 7;
  const int t = threadIdx.x;
  const int wv = t >> 6, l = t & 63;
  const int wm = wv >> 1, wn = wv & 1;

  __shared__ u16 Xs[128 * 64];
  __shared__ u16 Ws[128 * 64];

  const int crow = l >> 3;
  const int chunk = (l & 7) ^ (crow & 7);

  int gcol[4], sy[4], sx[4], sf[4];
  #pragma unroll
  for (int i = 0; i < 4; ++i) {
    gcol[i] = nt * 128 + wv * 32 + i * 8 + crow;
    int s = gcol[i] % HW_N;
    sy[i] = s / 28; sx[i] = s - (s / 28) * 28;
    sf[i] = (gcol[i] / HW_N) & 3;
  }

  f32x4 acc[4][4];
  #pragma unroll
  for (int fm = 0; fm < 4; ++fm)
    #pragma unroll
    for (int fn = 0; fn < 4; ++fn) acc[fm][fn] = (f32x4){0.f, 0.f, 0.f, 0.f};

  for (int tap = 0; tap < TAPS; ++tap) {
    const u16* xp[4];
    const u16* wp[4];
    int dy = 0, dx = 0, off;
    if (TAPS == 9) { dy = tap / 3; dx = tap - dy * 3; off = (dy - 1) * 28 + (dx - 1); }
    else           { off = (tap - 1) * HW_N; }
    #pragma unroll
    for (int i = 0; i < 4; ++i) {
      bool valid;
      if (TAPS == 9) {
        int yy = sy[i] + dy - 1, xx = sx[i] + dx - 1;
        valid = ((unsigned)yy < 28u) && ((unsigned)xx < 28u);
      } else {
        int ff = sf[i] + tap - 1;
        valid = ((unsigned)ff < 4u);
      }
      xp[i] = valid ? (xin + (size_t)(gcol[i] + off) * C_N + chunk * 8)
                    : (zbuf + chunk * 8);
      int co = cobase + wv * 32 + i * 8 + crow;
      wp[i] = wb + ((size_t)tap * C_N + co) * C_N + chunk * 8;
    }
    for (int kb = 0; kb < 8; ++kb) {
      __syncthreads();
      #pragma unroll
      for (int i = 0; i < 4; ++i) {
        gl_lds16(xp[i], (void*)(Xs + (wv * 4 + i) * 512));
        gl_lds16(wp[i], (void*)(Ws + (wv * 4 + i) * 512));
        xp[i] += 64; wp[i] += 64;
      }
      __syncthreads();
      const int lr = l & 15, lk = l >> 4;
      #pragma unroll
      for (int kk = 0; kk < 2; ++kk) {
        const int slotbase = kk * 4 + lk;
        bf16x8 af[4], bx[4];
        #pragma unroll
        for (int fm = 0; fm < 4; ++fm) {
          int row = wm * 64 + fm * 16 + lr;
          int slot = slotbase ^ (lr & 7);
          af[fm] = *(const bf16x8*)&Ws[row * 64 + slot * 8];
        }
        #pragma unroll
        for (int fn = 0; fn < 4; ++fn) {
          int col = wn * 64 + fn * 16 + lr;
          int slot = slotbase ^ (lr & 7);
          bx[fn] = *(const bf16x8*)&Xs[col * 64 + slot * 8];
        }
        #pragma unroll
        for (int fm = 0; fm < 4; ++fm)
          #pragma unroll
          for (int fn = 0; fn < 4; ++fn)
            acc[fm][fn] = __builtin_amdgcn_mfma_f32_16x16x32_bf16(
                af[fm], bx[fn], acc[fm][fn], 0, 0, 0);
      }
    }
  }

  const int lr = l & 15, lg = l >> 4;
  #pragma unroll
  for (int fn = 0; fn < 4; ++fn) {
    int n = nt * 128 + wn * 64 + fn * 16 + lr;
    if (OUTM == 1) {
      #pragma unroll
      for (int fm = 0; fm < 4; ++fm) {
        int co = cobase + wm * 64 + fm * 16 + lg * 4;
        ushort4 pk;
        pk.x = f2b(acc[fm][fn][0]); pk.y = f2b(acc[fm][fn][1]);
        pk.z = f2b(acc[fm][fn][2]); pk.w = f2b(acc[fm][fn][3]);
        *(ushort4*)&outp[(size_t)n * C_N + co] = pk;
      }
    } else {
      int bf = n / HW_N, s = n - (n / HW_N) * HW_N;
      int b = bf >> 2, f = bf & 3;
      #pragma unroll
      for (int fm = 0; fm < 4; ++fm) {
        int co = cobase + wm * 64 + fm * 16 + lg * 4;
        size_t base = ((size_t)(b * C_N + co)) * PL + (size_t)f * HW_N + s;
        outp[base]            = f2b(acc[fm][fn][0]);
        outp[base + PL]       = f2b(acc[fm][fn][1]);
        outp[base + 2 * PL]   = f2b(acc[fm][fn][2]);
        outp[base + 3 * PL]   = f2b(acc[fm][fn][3]);
      }
    }
  }
}

// ---------------- MFMA fused attention ----------------
// Per group (b, 16-ch slab): S = scale*([Qt;P]·[K;Q]), softmax rows (online),
// O = P·Vt, out = O + rel2. Head-dim axis permuted: e = fr*16 + c_off.
// q0,k0 channels-last bf16 [12544][512]; v0 planar bf16.
__global__ __launch_bounds__(256, 2) void attn_mfma(
    const u16* __restrict__ q0, const u16* __restrict__ k0,
    const u16* __restrict__ v0,
    const float* __restrict__ rel_h, const float* __restrict__ rel_w,
    const float* __restrict__ rel_t, const float* __restrict__ rel_h2,
    const float* __restrict__ rel_w2, const float* __restrict__ rel_t2,
    float* __restrict__ out)
{
  const int g = blockIdx.x, qt = blockIdx.y;
  const int b = g >> 5, gg = g & 31;
  const int cbase = gg << 4, h = gg >> 2, fgrp = gg & 3;
  const int qbase = min(qt * 128, 656);   // all q-rows < 784, overlap benign
  const int t = threadIdx.x;
  const int w = t >> 6, lane = t & 63, ll = lane & 15, lh = lane >> 4;

  __shared__ __align__(16) u16 smem[20480];        // 40 KB
  u16* Bp = smem;                                  // [64 k][128 d] swz
  u16* Vt = smem + 8192;                           // [64 e][64 k] swz
  u16* Pm = smem + 12288;                          // [128 q][64 k] swz
  float* Obuf = (float*)smem;                      // [64 e][130 q] (epilogue)

  const size_t slab = ((size_t)b * C_N + cbase) * PL;

  // ---- A-operand in registers: Qt (global) + P (computed), k-tile invariant
  bf16x8 afr[2][4];
  #pragma unroll
  for (int mf = 0; mf < 2; ++mf) {
    const int q = qbase + w * 32 + mf * 16 + ll;
    const int y = q / 28, x = q - (q / 28) * 28;
    #pragma unroll
    for (int kk = 0; kk < 2; ++kk) {
      int c = kk * 4 + lh;
      afr[mf][kk] = *(const bf16x8*)&q0[((size_t)((b * 4 + (c >> 1)) * HW_N + q)) * C_N
                                        + cbase + (c & 1) * 8];
    }
    #pragma unroll
    for (int kk = 0; kk < 2; ++kk) {
      int ebase = kk * 32 + lh * 8;
      bf16x8 pv;
      #pragma unroll
      for (int j = 0; j < 8; ++j) {
        int e = ebase + j;
        int di = (e & 15) * 4 + (e >> 4);
        int idx = h * 64 + di;
        pv[j] = (short)f2b(rel_h[idx * 28 + y] + rel_w[idx * 28 + x]
                           + rel_t[idx * 4 + fgrp]);
      }
      afr[mf][2 + kk] = pv;
    }
  }

  f32x4 oacc[2][4];
  float m_[2][4], l_[2][4];
  #pragma unroll
  for (int mf = 0; mf < 2; ++mf)
    #pragma unroll
    for (int r = 0; r < 4; ++r) {
      oacc[mf][r] = (f32x4){0.f, 0.f, 0.f, 0.f};
      m_[mf][r] = -1e30f; l_[mf][r] = 0.f;
    }
  #pragma unroll
  for (int mf = 0; mf < 2; ++mf)
    #pragma unroll
    for (int nf = 0; nf < 4; ++nf) oacc[mf][nf] = (f32x4){0.f, 0.f, 0.f, 0.f};

  for (int kt = 0; kt < 13; ++kt) {
    const int kbase = kt * 64;
    __syncthreads();                       // prev tile's LDS reads done
    // ---- stage B' = [K;Q] rows (4x) and Vt rows (2x), pre-swizzled source
    #pragma unroll
    for (int i = 0; i < 4; ++i) {
      int krow = w * 16 + i * 4 + lh;
      int c = (ll & 8) | ((ll ^ krow) & 7);
      int cc = c & 7;
      const u16* base = (c < 8) ? k0 : q0;
      const u16* src = base + ((size_t)((b * 4 + (cc >> 1)) * HW_N + kbase + krow)) * C_N
                       + cbase + (cc & 1) * 8;
      gl_lds16(src, (void*)(Bp + (w * 16 + i * 4) * 128));
    }
    #pragma unroll
    for (int i = 0; i < 2; ++i) {
      int e = w * 16 + i * 8 + (lane >> 3);
      int ch = (lane & 7) ^ (e & 7);
      int di = (e & 15) * 4 + (e >> 4);
      const u16* src = v0 + slab + (size_t)di * HW_N + kbase + ch * 8;
      gl_lds16(src, (void*)(Vt + (w * 16 + i * 8) * 64));
    }
    __syncthreads();                       // staging complete

    // ---- S = A' * B'
    f32x4 sacc[2][4];
    #pragma unroll
    for (int mf = 0; mf < 2; ++mf)
      #pragma unroll
      for (int nf = 0; nf < 4; ++nf) sacc[mf][nf] = (f32x4){0.f, 0.f, 0.f, 0.f};
    #pragma unroll
    for (int kk = 0; kk < 4; ++kk) {
      bf16x8 bx[4];
      #pragma unroll
      for (int nf = 0; nf < 4; ++nf) {
        int slot = (kk * 4 + lh) ^ (ll & 7);
        bx[nf] = *(const bf16x8*)&Bp[(nf * 16 + ll) * 128 + slot * 8];
      }
      #pragma unroll
      for (int mf = 0; mf < 2; ++mf)
        #pragma unroll
        for (int nf = 0; nf < 4; ++nf)
          sacc[mf][nf] = __builtin_amdgcn_mfma_f32_16x16x32_bf16(
              afr[mf][kk], bx[nf], sacc[mf][nf], 0, 0, 0);
    }

    // ---- online softmax (in-wave; rows = q, cols = 64 k of this tile)
    bool kval[4];
    #pragma unroll
    for (int nf = 0; nf < 4; ++nf) kval[nf] = (kbase + nf * 16 + ll) < HW_N;
    #pragma unroll
    for (int mf = 0; mf < 2; ++mf) {
      const int qlb = w * 32 + mf * 16;
      #pragma unroll
      for (int r = 0; r < 4; ++r) {
        float s0 = kval[0] ? sacc[mf][0][r] * SCALE_F : -1e30f;
        float s1 = kval[1] ? sacc[mf][1][r] * SCALE_F : -1e30f;
        float s2 = kval[2] ? sacc[mf][2][r] * SCALE_F : -1e30f;
        float s3 = kval[3] ? sacc[mf][3][r] * SCALE_F : -1e30f;
        float rmax = fmaxf(fmaxf(s0, s1), fmaxf(s2, s3));
        #pragma unroll
        for (int off = 8; off >= 1; off >>= 1)
          rmax = fmaxf(rmax, __shfl_xor(rmax, off));
        float mn = fmaxf(m_[mf][r], rmax);
        float sc = __expf(m_[mf][r] - mn);
        float p0 = __expf(s0 - mn), p1 = __expf(s1 - mn);
        float p2 = __expf(s2 - mn), p3 = __expf(s3 - mn);
        float psum = (p0 + p1) + (p2 + p3);
        #pragma unroll
        for (int off = 8; off >= 1; off >>= 1)
          psum += __shfl_xor(psum, off);
        l_[mf][r] = l_[mf][r] * sc + psum;
        m_[mf][r] = mn;
        const int ql = qlb + lh * 4 + r;
        const int swz = (ql & 7);
        Pm[ql * 64 + (((ll >> 3)      ^ swz) * 8) + (ll & 7)] = f2b(p0);
        Pm[ql * 64 + (((2 + (ll >> 3)) ^ swz) * 8) + (ll & 7)] = f2b(p1);
        Pm[ql * 64 + (((4 + (ll >> 3)) ^ swz) * 8) + (ll & 7)] = f2b(p2);
        Pm[ql * 64 + (((6 + (ll >> 3)) ^ swz) * 8) + (ll & 7)] = f2b(p3);
        #pragma unroll
        for (int nf = 0; nf < 4; ++nf) oacc[mf][nf][r] *= sc;
      }
    }
    // Pm rows are written and read by the SAME wave -> no barrier needed.

    // ---- O += P * Vt
    #pragma unroll
    for (int ks = 0; ks < 2; ++ks) {
      bf16x8 pa[2], vb[4];
      #pragma unroll
      for (int mf = 0; mf < 2; ++mf) {
        int ql = w * 32 + mf * 16 + ll;
        int slot = (ks * 4 + lh) ^ (ql & 7);
        pa[mf] = *(const bf16x8*)&Pm[ql * 64 + slot * 8];
      }
      #pragma unroll
      for (int nf = 0; nf < 4; ++nf) {
        int e = nf * 16 + ll;
        int slot = (ks * 4 + lh) ^ (e & 7);
        vb[nf] = *(const bf16x8*)&Vt[e * 64 + slot * 8];
      }
      #pragma unroll
      for (int mf = 0; mf < 2; ++mf)
        #pragma unroll
        for (int nf = 0; nf < 4; ++nf)
          oacc[mf][nf] = __builtin_amdgcn_mfma_f32_16x16x32_bf16(
              pa[mf], vb[nf], oacc[mf][nf], 0, 0, 0);
    }
  }

  // ---- epilogue: O/l -> Obuf (transpose), then coalesced store + rel2
  __syncthreads();
  float rinv[2][4];
  #pragma unroll
  for (int mf = 0; mf < 2; ++mf)
    #pragma unroll
    for (int r = 0; r < 4; ++r) rinv[mf][r] = 1.f / l_[mf][r];
  #pragma unroll
  for (int mf = 0; mf < 2; ++mf)
    #pragma unroll
    for (int nf = 0; nf < 4; ++nf)
      #pragma unroll
      for (int r = 0; r < 4; ++r)
        Obuf[(nf * 16 + ll) * 130 + w * 32 + mf * 16 + lh * 4 + r] =
            oacc[mf][nf][r] * rinv[mf][r];
  __syncthreads();
  #pragma unroll 4
  for (int j = 0; j < 32; ++j) {
    int idx = t + 256 * j;           // 0..8191
    int e = idx >> 7, ql = idx & 127;
    int s = qbase + ql;
    int c = cbase + (e & 15), fr = e >> 4;
    int y = s / 28, x = s - (s / 28) * 28;
    out[(((size_t)(b * C_N + c)) * 4 + fr) * HW_N + s] =
        Obuf[e * 130 + ql] + rel_t2[c * 4 + fr] + rel_h2[c * 28 + y]
        + rel_w2[c * 28 + x];
  }
}

extern "C" void kernel_launch(void* const* d_in, const int* in_sizes, int n_in,
                              void* d_out, int out_size, void* d_ws, size_t ws_size,
                              hipStream_t stream) {
  const float* x     = (const float*)d_in[0];
  const float* Wq    = (const float*)d_in[1];
  const float* Wk    = (const float*)d_in[2];
  const float* Wv1   = (const float*)d_in[3];
  const float* Wv2   = (const float*)d_in[4];
  const float* relh  = (const float*)d_in[5];
  const float* relw  = (const float*)d_in[6];
  const float* relt  = (const float*)d_in[7];
  const float* relh2 = (const float*)d_in[8];
  const float* relw2 = (const float*)d_in[9];
  const float* relt2 = (const float*)d_in[10];
  float* out = (float*)d_out;
  char* ws = (char*)d_ws;

  const size_t NE = (size_t)NTOT * C_N;
  u16* xt   = (u16*)(ws);
  u16* tq   = (u16*)(ws + NE * 2);   // v1 temp, then q0 (channels-last)
  u16* k0   = (u16*)(ws + NE * 4);   // channels-last
  u16* v0   = (u16*)(ws + NE * 6);   // planar
  u16* wqb  = (u16*)(ws + NE * 8);
  u16* wkb  = (u16*)(ws + NE * 8 + 4718592);
  u16* wv1b = (u16*)(ws + NE * 8 + 4718592 + 1572864);
  u16* wv2b = (u16*)(ws + NE * 8 + 4718592 + 2 * 1572864);
  u16* zbuf = (u16*)(ws + NE * 8 + 2 * 4718592 + 2 * 1572864);

  zerok<<<dim3(4), dim3(256), 0, stream>>>((float*)zbuf);
  pack_w<9><<<dim3(9216), dim3(256), 0, stream>>>(Wq,  wqb,  9 * C_N * C_N);
  pack_w<3><<<dim3(3072), dim3(256), 0, stream>>>(Wk,  wkb,  3 * C_N * C_N);
  pack_w<3><<<dim3(3072), dim3(256), 0, stream>>>(Wv1, wv1b, 3 * C_N * C_N);
  pack_w<9><<<dim3(9216), dim3(256), 0, stream>>>(Wv2, wv2b, 9 * C_N * C_N);
  cast_transpose<<<dim3(16, 13, 8), dim3(256), 0, stream>>>(x, xt);

  dim3 cgrid(98, 4), blk(256);
  conv_mfma<3, 1><<<cgrid, blk, 0, stream>>>(xt, wv1b, tq, zbuf);   // v1 (cl)
  conv_mfma<9, 2><<<cgrid, blk, 0, stream>>>(tq, wv2b, v0, zbuf);   // v (planar)
  conv_mfma<3, 1><<<cgrid, blk, 0, stream>>>(xt, wkb, k0, zbuf);    // k (cl)
  conv_mfma<9, 1><<<cgrid, blk, 0, stream>>>(xt, wqb, tq, zbuf);    // q (cl)

  attn_mfma<<<dim3(128, 7), blk, 0, stream>>>(
      tq, k0, v0, relh, relw, relt, relh2, relw2, relt2, out);
}